// Round 1
// baseline (451.998 us; speedup 1.0000x reference)
//
#include <hip/hip_runtime.h>
#include <math.h>

// Problem constants (from reference): B=8, T=4096, D=2048, W=4, fp32 in/out.
#define CB 8
#define CT 4096
#define CD 2048
#define CW 4
#define TC 32          // t-steps per thread (halo = 3/32 ~ 9% extra reads,
                       //  buys 2048 blocks -> 8 blocks/CU -> 32 waves/CU)
#define D4 (CD / 4)    // 512 float4 lanes across D

typedef float v4f __attribute__((ext_vector_type(4)));

__device__ __forceinline__ float silu1(float v) {
    // v * sigmoid(v); sigmoid = rcp(1 + exp(-v)).
    // v_exp_f32 + v_rcp_f32 (~1 ulp) instead of the precise-div sequence.
    return v * __builtin_amdgcn_rcpf(1.f + __expf(-v));
}

__device__ __forceinline__ float4 conv_silu(const float4 w0, const float4 w1,
                                            const float4 w2, const float4 w3,
                                            const float4 a, const float4 b,
                                            const float4 c, const float4 d) {
    float4 r;
    r.x = silu1(w0.x * a.x + w1.x * b.x + w2.x * c.x + w3.x * d.x);
    r.y = silu1(w0.y * a.y + w1.y * b.y + w2.y * c.y + w3.y * d.y);
    r.z = silu1(w0.z * a.z + w1.z * b.z + w2.z * c.z + w3.z * d.z);
    r.w = silu1(w0.w * a.w + w1.w * b.w + w2.w * c.w + w3.w * d.w);
    return r;
}

__global__ __launch_bounds__(256) void conv_silu_kernel(
    const float4* __restrict__ x,      // [B, T, D4]
    const float4* __restrict__ w,      // [W, D4]
    float4* __restrict__ out)          // [B, T, D4]
{
    const int d4 = blockIdx.x * 256 + threadIdx.x;  // 0..D4-1
    const int t0 = blockIdx.y * TC;
    const int b  = blockIdx.z;

    // Pre-offset by d4: row indexing below is a single multiply-add.
    const float4* xb = x   + (size_t)b * CT * D4 + d4;
    float4*       ob = out + (size_t)b * CT * D4 + d4;

    // Per-channel weights (4 float4 = 16 fp32), read once, L2-cached.
    const float4 w0 = w[0 * D4 + d4];
    const float4 w1 = w[1 * D4 + d4];
    const float4 w2 = w[2 * D4 + d4];
    const float4 w3 = w[3 * D4 + d4];

    // Rolling window x[t-3], x[t-2], x[t-1]. t0 is a multiple of TC (>=4),
    // so only the t0==0 chunk touches the causal zero-pad.
    float4 xm3 = make_float4(0.f, 0.f, 0.f, 0.f);
    float4 xm2 = xm3;
    float4 xm1 = xm3;
    if (t0 > 0) {
        xm3 = xb[(size_t)(t0 - 3) * D4];
        xm2 = xb[(size_t)(t0 - 2) * D4];
        xm1 = xb[(size_t)(t0 - 1) * D4];
    }

    // 8 iterations of {4 independent loads -> 4 conv+silu -> 4 nt stores}.
    // Loads are issued as a batch (independent of the rolling-window chain)
    // so 4 global_load_dwordx4 are in flight per wave; with 32 waves/CU
    // that is ~128 KB outstanding per CU, far above the ~10 KB needed to
    // cover ~900-cycle HBM latency at the per-CU BW share.
#pragma unroll 1
    for (int t = t0; t < t0 + TC; t += 4) {
        const size_t base = (size_t)t * D4;
        const float4 x0 = xb[base + 0 * D4];
        const float4 x1 = xb[base + 1 * D4];
        const float4 x2 = xb[base + 2 * D4];
        const float4 x3 = xb[base + 3 * D4];

        float4 y0 = conv_silu(w0, w1, w2, w3, xm3, xm2, xm1, x0);
        float4 y1 = conv_silu(w0, w1, w2, w3, xm2, xm1, x0,  x1);
        float4 y2 = conv_silu(w0, w1, w2, w3, xm1, x0,  x1,  x2);
        float4 y3 = conv_silu(w0, w1, w2, w3, x0,  x1,  x2,  x3);

        // Output is never re-read: nontemporal stores keep it from
        // competing for L2 with the input stream.
        __builtin_nontemporal_store(*(const v4f*)&y0, (v4f*)(ob + base + 0 * D4));
        __builtin_nontemporal_store(*(const v4f*)&y1, (v4f*)(ob + base + 1 * D4));
        __builtin_nontemporal_store(*(const v4f*)&y2, (v4f*)(ob + base + 2 * D4));
        __builtin_nontemporal_store(*(const v4f*)&y3, (v4f*)(ob + base + 3 * D4));

        xm3 = x1;
        xm2 = x2;
        xm1 = x3;
    }
}

extern "C" void kernel_launch(void* const* d_in, const int* in_sizes, int n_in,
                              void* d_out, int out_size, void* d_ws, size_t ws_size,
                              hipStream_t stream) {
    const float4* x = (const float4*)d_in[0];   // [B,T,D] fp32
    const float4* w = (const float4*)d_in[1];   // [W,1,D] fp32
    float4* out = (float4*)d_out;               // [B,T,D] fp32

    dim3 block(256);
    dim3 grid(D4 / 256, CT / TC, CB);           // (2, 128, 8) = 2048 blocks
    conv_silu_kernel<<<grid, block, 0, stream>>>(x, w, out);
}

// Round 2
// 438.119 us; speedup vs baseline: 1.0317x; 1.0317x over previous
//
#include <hip/hip_runtime.h>
#include <math.h>

// Problem constants (from reference): B=8, T=4096, D=2048, W=4, fp32 in/out.
#define CB 8
#define CT 4096
#define CD 2048
#define CW 4
#define TC 32          // t-steps per thread: 2048 blocks -> 8 blocks/CU -> 32 waves/CU
#define D4 (CD / 4)    // 512 float4 lanes across D

__device__ __forceinline__ float silu1(float v) {
    // v * sigmoid(v); sigmoid = rcp(1 + exp(-v)).  v_exp_f32 + v_rcp_f32 (~1 ulp).
    return v * __builtin_amdgcn_rcpf(1.f + __expf(-v));
}

__device__ __forceinline__ float4 conv_silu(const float4 w0, const float4 w1,
                                            const float4 w2, const float4 w3,
                                            const float4 a, const float4 b,
                                            const float4 c, const float4 d) {
    float4 r;
    r.x = silu1(w0.x * a.x + w1.x * b.x + w2.x * c.x + w3.x * d.x);
    r.y = silu1(w0.y * a.y + w1.y * b.y + w2.y * c.y + w3.y * d.y);
    r.z = silu1(w0.z * a.z + w1.z * b.z + w2.z * c.z + w3.z * d.z);
    r.w = silu1(w0.w * a.w + w1.w * b.w + w2.w * c.w + w3.w * d.w);
    return r;
}

__global__ __launch_bounds__(256) void conv_silu_kernel(
    const float4* __restrict__ x,      // [B, T, D4]
    const float4* __restrict__ w,      // [W, D4]
    float4* __restrict__ out)          // [B, T, D4]
{
    const int d4 = blockIdx.x * 256 + threadIdx.x;  // 0..D4-1
    const int t0 = blockIdx.y * TC;
    const int b  = blockIdx.z;

    const float4* xb = x   + (size_t)b * CT * D4 + d4;
    float4*       ob = out + (size_t)b * CT * D4 + d4;

    // Per-channel weights (4 float4 = 16 fp32), read once, L2-cached.
    const float4 w0 = w[0 * D4 + d4];
    const float4 w1 = w[1 * D4 + d4];
    const float4 w2 = w[2 * D4 + d4];
    const float4 w3 = w[3 * D4 + d4];

    // Rolling window x[t-3], x[t-2], x[t-1]. t0 is a multiple of TC (>=4),
    // so only the t0==0 chunk touches the causal zero-pad.
    float4 xm3 = make_float4(0.f, 0.f, 0.f, 0.f);
    float4 xm2 = xm3;
    float4 xm1 = xm3;
    if (t0 > 0) {
        xm3 = xb[(size_t)(t0 - 3) * D4];
        xm2 = xb[(size_t)(t0 - 2) * D4];
        xm1 = xb[(size_t)(t0 - 1) * D4];
    }

    // Software pipeline: issue iteration i+1's loads BEFORE iteration i's
    // stores. vmcnt retires in issue order, so the wait for next-iter
    // compute then sits AHEAD of the stores in the queue and never chains
    // on store retirement (loads+stores share vmcnt — the round-1 trap).
    size_t base = (size_t)t0 * D4;
    float4 c0 = xb[base + 0 * D4];
    float4 c1 = xb[base + 1 * D4];
    float4 c2 = xb[base + 2 * D4];
    float4 c3 = xb[base + 3 * D4];

#pragma unroll 1
    for (int t = t0; t < t0 + TC - 4; t += 4) {
        base = (size_t)t * D4;
        // Prefetch next group of 4 rows (independent of current compute).
        const float4 n0 = xb[base + 4 * D4];
        const float4 n1 = xb[base + 5 * D4];
        const float4 n2 = xb[base + 6 * D4];
        const float4 n3 = xb[base + 7 * D4];

        float4 y0 = conv_silu(w0, w1, w2, w3, xm3, xm2, xm1, c0);
        float4 y1 = conv_silu(w0, w1, w2, w3, xm2, xm1, c0,  c1);
        float4 y2 = conv_silu(w0, w1, w2, w3, xm1, c0,  c1,  c2);
        float4 y3 = conv_silu(w0, w1, w2, w3, c0,  c1,  c2,  c3);

        ob[base + 0 * D4] = y0;
        ob[base + 1 * D4] = y1;
        ob[base + 2 * D4] = y2;
        ob[base + 3 * D4] = y3;

        xm3 = c1; xm2 = c2; xm1 = c3;
        c0 = n0; c1 = n1; c2 = n2; c3 = n3;
    }

    // Epilogue: last group of 4 rows (already loaded).
    base = (size_t)(t0 + TC - 4) * D4;
    float4 y0 = conv_silu(w0, w1, w2, w3, xm3, xm2, xm1, c0);
    float4 y1 = conv_silu(w0, w1, w2, w3, xm2, xm1, c0,  c1);
    float4 y2 = conv_silu(w0, w1, w2, w3, xm1, c0,  c1,  c2);
    float4 y3 = conv_silu(w0, w1, w2, w3, c0,  c1,  c2,  c3);
    ob[base + 0 * D4] = y0;
    ob[base + 1 * D4] = y1;
    ob[base + 2 * D4] = y2;
    ob[base + 3 * D4] = y3;
}

extern "C" void kernel_launch(void* const* d_in, const int* in_sizes, int n_in,
                              void* d_out, int out_size, void* d_ws, size_t ws_size,
                              hipStream_t stream) {
    const float4* x = (const float4*)d_in[0];   // [B,T,D] fp32
    const float4* w = (const float4*)d_in[1];   // [W,1,D] fp32
    float4* out = (float4*)d_out;               // [B,T,D] fp32

    dim3 block(256);
    dim3 grid(D4 / 256, CT / TC, CB);           // (2, 128, 8) = 2048 blocks
    conv_silu_kernel<<<grid, block, 0, stream>>>(x, w, out);
}

// Round 3
// 436.912 us; speedup vs baseline: 1.0345x; 1.0028x over previous
//
#include <hip/hip_runtime.h>
#include <math.h>

// Problem constants (from reference): B=8, T=4096, D=2048, W=4, fp32 in/out.
#define CB 8
#define CT 4096
#define CD 2048
#define CW 4
#define TC 32          // t-steps per thread: 1024 blocks x 8 waves -> 32 waves/CU
#define D4 (CD / 4)    // 512 float4 lanes across D == one full 8 KB row per block

__device__ __forceinline__ float silu1(float v) {
    // v * sigmoid(v); sigmoid = rcp(1 + exp(-v)).  v_exp_f32 + v_rcp_f32 (~1 ulp).
    return v * __builtin_amdgcn_rcpf(1.f + __expf(-v));
}

__device__ __forceinline__ float4 conv_silu(const float4 w0, const float4 w1,
                                            const float4 w2, const float4 w3,
                                            const float4 a, const float4 b,
                                            const float4 c, const float4 d) {
    float4 r;
    r.x = silu1(w0.x * a.x + w1.x * b.x + w2.x * c.x + w3.x * d.x);
    r.y = silu1(w0.y * a.y + w1.y * b.y + w2.y * c.y + w3.y * d.y);
    r.z = silu1(w0.z * a.z + w1.z * b.z + w2.z * c.z + w3.z * d.z);
    r.w = silu1(w0.w * a.w + w1.w * b.w + w2.w * c.w + w3.w * d.w);
    return r;
}

// Block = 512 threads = full D row (512 float4 = 8 KB = one row of x).
// Consecutive t rows are contiguous in memory, so each block's read stream
// is a dense linear 256 KB slab (+ 24 KB linear halo prefix) and its write
// stream a dense linear 256 KB slab — vs the previous 4 KB-chunk / 8 KB-stride
// pattern from half-row blocks. Tests the DRAM row-buffer-locality theory.
__global__ __launch_bounds__(512) void conv_silu_kernel(
    const float4* __restrict__ x,      // [B, T, D4]
    const float4* __restrict__ w,      // [W, D4]
    float4* __restrict__ out)          // [B, T, D4]
{
    const int d4 = threadIdx.x;        // 0..D4-1 (full row per block)
    const int t0 = blockIdx.x * TC;
    const int b  = blockIdx.y;

    const float4* xb = x   + (size_t)b * CT * D4 + d4;
    float4*       ob = out + (size_t)b * CT * D4 + d4;

    // Per-channel weights (4 float4 = 16 fp32), read once, L2-cached.
    const float4 w0 = w[0 * D4 + d4];
    const float4 w1 = w[1 * D4 + d4];
    const float4 w2 = w[2 * D4 + d4];
    const float4 w3 = w[3 * D4 + d4];

    // Rolling window x[t-3], x[t-2], x[t-1]. t0 is a multiple of TC (>=4),
    // so only the t0==0 chunk touches the causal zero-pad.
    float4 xm3 = make_float4(0.f, 0.f, 0.f, 0.f);
    float4 xm2 = xm3;
    float4 xm1 = xm3;
    if (t0 > 0) {
        xm3 = xb[(size_t)(t0 - 3) * D4];
        xm2 = xb[(size_t)(t0 - 2) * D4];
        xm1 = xb[(size_t)(t0 - 1) * D4];
    }

    // Software pipeline: issue group i+1's loads BEFORE group i's stores so
    // the vmcnt wait for the next compute never chains on store retirement
    // (loads and stores share the in-order vmcnt counter).
    size_t base = (size_t)t0 * D4;
    float4 c0 = xb[base + 0 * D4];
    float4 c1 = xb[base + 1 * D4];
    float4 c2 = xb[base + 2 * D4];
    float4 c3 = xb[base + 3 * D4];

#pragma unroll 1
    for (int t = t0; t < t0 + TC - 4; t += 4) {
        base = (size_t)t * D4;
        // Prefetch next group of 4 rows (independent of current compute).
        const float4 n0 = xb[base + 4 * D4];
        const float4 n1 = xb[base + 5 * D4];
        const float4 n2 = xb[base + 6 * D4];
        const float4 n3 = xb[base + 7 * D4];

        float4 y0 = conv_silu(w0, w1, w2, w3, xm3, xm2, xm1, c0);
        float4 y1 = conv_silu(w0, w1, w2, w3, xm2, xm1, c0,  c1);
        float4 y2 = conv_silu(w0, w1, w2, w3, xm1, c0,  c1,  c2);
        float4 y3 = conv_silu(w0, w1, w2, w3, c0,  c1,  c2,  c3);

        ob[base + 0 * D4] = y0;
        ob[base + 1 * D4] = y1;
        ob[base + 2 * D4] = y2;
        ob[base + 3 * D4] = y3;

        xm3 = c1; xm2 = c2; xm1 = c3;
        c0 = n0; c1 = n1; c2 = n2; c3 = n3;
    }

    // Epilogue: last group of 4 rows (already loaded).
    base = (size_t)(t0 + TC - 4) * D4;
    float4 y0 = conv_silu(w0, w1, w2, w3, xm3, xm2, xm1, c0);
    float4 y1 = conv_silu(w0, w1, w2, w3, xm2, xm1, c0,  c1);
    float4 y2 = conv_silu(w0, w1, w2, w3, xm1, c0,  c1,  c2);
    float4 y3 = conv_silu(w0, w1, w2, w3, c0,  c1,  c2,  c3);
    ob[base + 0 * D4] = y0;
    ob[base + 1 * D4] = y1;
    ob[base + 2 * D4] = y2;
    ob[base + 3 * D4] = y3;
}

extern "C" void kernel_launch(void* const* d_in, const int* in_sizes, int n_in,
                              void* d_out, int out_size, void* d_ws, size_t ws_size,
                              hipStream_t stream) {
    const float4* x = (const float4*)d_in[0];   // [B,T,D] fp32
    const float4* w = (const float4*)d_in[1];   // [W,1,D] fp32
    float4* out = (float4*)d_out;               // [B,T,D] fp32

    dim3 block(512);
    dim3 grid(CT / TC, CB);                     // (128, 8) = 1024 blocks, 4/CU
    conv_silu_kernel<<<grid, block, 0, stream>>>(x, w, out);
}